// Round 10
// baseline (1091.026 us; speedup 1.0000x reference)
//
#include <hip/hip_runtime.h>
#include <math.h>

#define D_MODEL 512
#define D_INNER 1024
#define DT_RANK 32
#define D_STATE 16
#define D_CONV 4
#define NB_LAYERS 3
#define BATCH 64
#define SEQ 201
#define CITY 200
#define M_ROWS (BATCH * SEQ)   // 12864 = 64*201
#define M_PAD 12928            // 128*101, for 128-row MFMA tiles
#define EPS 1e-5f
#define ST 16                  // scan timestep tile

typedef __attribute__((ext_vector_type(8))) short short8;
typedef __attribute__((ext_vector_type(8))) unsigned short ushort8;
typedef __attribute__((ext_vector_type(4))) float f32x4;

__device__ __forceinline__ float sigmoidf_(float x) { return 1.f / (1.f + __expf(-x)); }

__device__ __forceinline__ unsigned short f2b(float f) {  // RNE fp32->bf16
  union { float f; unsigned int u; } v; v.f = f;
  unsigned int r = (v.u + 0x7fff + ((v.u >> 16) & 1)) >> 16;
  return (unsigned short)r;
}
__device__ __forceinline__ float b2f(unsigned short h) {
  union { unsigned int u; float f; } v; v.u = ((unsigned int)h) << 16; return v.f;
}

__device__ __forceinline__ void gload_lds16(const void* g, void* l) {
  __builtin_amdgcn_global_load_lds(
      (const __attribute__((address_space(1))) void*)g,
      (__attribute__((address_space(3))) void*)l, 16, 0, 0);
}

// ---------------- fp32 -> bf16 bulk convert (zero-pad tail to n_total) ----------------
__global__ __launch_bounds__(256) void k_f2b(const float* __restrict__ in,
                                             unsigned short* __restrict__ out,
                                             int n, int n_total) {
  int i = blockIdx.x * 256 + threadIdx.x;
  if (i < n) out[i] = f2b(in[i]);
  else if (i < n_total) out[i] = 0;
}

// ---------------- fp32 [rows][incols] -> bf16 [rows][outcols], zero col-pad ----------------
__global__ __launch_bounds__(256) void k_padW(const float* __restrict__ W,
                                              unsigned short* __restrict__ out,
                                              int rows, int incols, int outcols) {
  int i = blockIdx.x * 256 + threadIdx.x;
  if (i >= rows * outcols) return;
  int n = i / outcols, k = i - n * outcols;
  out[i] = (k < incols) ? f2b(W[(size_t)n * incols + k]) : 0;
}

// ---------------- embed ----------------
__global__ __launch_bounds__(256) void k_embed(const float* __restrict__ x,
                                               const float* __restrict__ W,
                                               const float* __restrict__ b,
                                               float* __restrict__ h) {
  int idx = blockIdx.x * 256 + threadIdx.x;
  if (idx >= M_ROWS * D_MODEL) return;
  int d = idx & (D_MODEL - 1);
  int m = idx >> 9;
  float x0 = x[m * 2 + 0], x1 = x[m * 2 + 1];
  h[idx] = fmaf(x0, W[d * 2 + 0], fmaf(x1, W[d * 2 + 1], b[d]));
}

// ---------------- fused residual add + LayerNorm / RMSNorm ----------------
__global__ __launch_bounds__(256) void k_resid_norm(const float* __restrict__ h,
                                                    float* __restrict__ resid,
                                                    float* __restrict__ out,
                                                    unsigned short* __restrict__ out_b,
                                                    const float* __restrict__ w,
                                                    const float* __restrict__ b,
                                                    int addRes, int mode) {
  int row = blockIdx.x * 4 + (threadIdx.x >> 6);
  int lane = threadIdx.x & 63;
  if (row >= M_ROWS) return;
  const float* hp = h + (size_t)row * D_MODEL;
  float* rp = resid + (size_t)row * D_MODEL;
  float v[8];
#pragma unroll
  for (int j = 0; j < 8; ++j) {
    float t = hp[j * 64 + lane];
    if (addRes) t += rp[j * 64 + lane];
    v[j] = t;
    rp[j * 64 + lane] = t;
  }
  float mu = 0.f, rstd;
  if (mode == 0) {
    float s = 0.f;
#pragma unroll
    for (int j = 0; j < 8; ++j) s += v[j];
#pragma unroll
    for (int o = 1; o < 64; o <<= 1) s += __shfl_xor(s, o);
    mu = s * (1.f / D_MODEL);
    float vs = 0.f;
#pragma unroll
    for (int j = 0; j < 8; ++j) { float d0 = v[j] - mu; vs += d0 * d0; }
#pragma unroll
    for (int o = 1; o < 64; o <<= 1) vs += __shfl_xor(vs, o);
    rstd = rsqrtf(vs * (1.f / D_MODEL) + EPS);
  } else {
    float s = 0.f;
#pragma unroll
    for (int j = 0; j < 8; ++j) s += v[j] * v[j];
#pragma unroll
    for (int o = 1; o < 64; o <<= 1) s += __shfl_xor(s, o);
    rstd = rsqrtf(s * (1.f / D_MODEL) + EPS);
  }
#pragma unroll
  for (int j = 0; j < 8; ++j) {
    int c = j * 64 + lane;
    float o = (v[j] - mu) * rstd * w[c] + b[c];
    if (out) out[(size_t)row * D_MODEL + c] = o;
    if (out_b) out_b[(size_t)row * D_MODEL + c] = f2b(o);
  }
}

// ---------------- bf16 MFMA GEMM: C[M,Nout] = A[M,K]bf16 @ B[N,K]bf16^T (+bias)(+softplus) --
// BM=BN=128, BK=64, 256 threads (4 waves, 2x2 of 64x64). Ngrid%128==0, K%64==0.
// BOUT=1 -> bf16 output, else fp32. ACT=1 -> +bias[col], softplus. Guard: m<M && col<Nout.
template <int BOUT, int ACT>
__global__ __launch_bounds__(256) void k_gemm_mfma(const unsigned short* __restrict__ A,
                                                   const unsigned short* __restrict__ B,
                                                   const float* __restrict__ bias,
                                                   void* __restrict__ Cv, int ldc,
                                                   int M, int Nout, int K) {
  __shared__ unsigned short lA[128 * 64];
  __shared__ unsigned short lB[128 * 64];
  int tid = threadIdx.x;
  int wave = tid >> 6, lane = tid & 63;
  int bm = blockIdx.y * 128, bn = blockIdx.x * 128;
  int wm = (wave >> 1) * 64, wn = (wave & 1) * 64;
  f32x4 acc[4][4] = {};

  for (int k0 = 0; k0 < K; k0 += 64) {
#pragma unroll
    for (int i = 0; i < 4; ++i) {
      int e = (i * 256 + tid) * 8;   // flat bf16 element in [128][64] tile
      int r = e >> 6, c = e & 63;
      gload_lds16(A + (size_t)(bm + r) * K + k0 + c, &lA[e]);
      gload_lds16(B + (size_t)(bn + r) * K + k0 + c, &lB[e]);
    }
    __syncthreads();
#pragma unroll
    for (int ks = 0; ks < 2; ++ks) {
      int koff = ks * 32 + (lane >> 4) * 8;
      short8 a[4], b[4];
#pragma unroll
      for (int i = 0; i < 4; ++i)
        a[i] = *(const short8*)&lA[(wm + i * 16 + (lane & 15)) * 64 + koff];
#pragma unroll
      for (int j = 0; j < 4; ++j)
        b[j] = *(const short8*)&lB[(wn + j * 16 + (lane & 15)) * 64 + koff];
#pragma unroll
      for (int i = 0; i < 4; ++i)
#pragma unroll
        for (int j = 0; j < 4; ++j)
          acc[i][j] = __builtin_amdgcn_mfma_f32_16x16x32_bf16(a[i], b[j], acc[i][j], 0, 0, 0);
    }
    __syncthreads();
  }
  // C/D layout: col = lane&15, row = (lane>>4)*4 + reg   [m89-verified]
#pragma unroll
  for (int i = 0; i < 4; ++i) {
    int row0 = bm + wm + i * 16 + (lane >> 4) * 4;
#pragma unroll
    for (int j = 0; j < 4; ++j) {
      int col = bn + wn + j * 16 + (lane & 15);
#pragma unroll
      for (int r = 0; r < 4; ++r) {
        int m = row0 + r;
        if (m < M && col < Nout) {
          float v = acc[i][j][r];
          if (ACT) { v += bias[col]; v = (v > 20.f) ? v : __logf(1.f + __expf(v)); }
          if (BOUT) ((unsigned short*)Cv)[(size_t)m * ldc + col] = f2b(v);
          else ((float*)Cv)[(size_t)m * ldc + col] = v;
        }
      }
    }
  }
}

// ---------------- depthwise causal conv (width 4) + bias + SiLU; bf16 in/out --------------
__global__ __launch_bounds__(256) void k_conv_silu(const unsigned short* __restrict__ xz,
                                                   const float* __restrict__ cw,
                                                   const float* __restrict__ cb,
                                                   unsigned short* __restrict__ ub) {
  int idx = blockIdx.x * 256 + threadIdx.x;
  if (idx >= M_ROWS * D_INNER) return;
  int d = idx & (D_INNER - 1);
  int m = idx >> 10;
  int l = m % SEQ;
  float acc = cb[d];
#pragma unroll
  for (int k = 0; k < D_CONV; ++k) {
    int ls = l - (D_CONV - 1) + k;
    if (ls >= 0)
      acc = fmaf(cw[d * D_CONV + k], b2f(xz[(size_t)(m - (D_CONV - 1) + k) * 2048 + d]), acc);
  }
  ub[idx] = f2b(acc * sigmoidf_(acc));
}

// ---------------- selective scan + D-skip + z-gate (lean: no LDS, no barriers) ----------
// 1 thread/channel. Per 16-step tile: batch-issue u/z/dt loads (one drain). Per step:
// B/C as 4 wave-uniform 16B loads from bf16 xdbl (L1-resident) + b2f. Only hst chains serial.
// Tail loads unconditional (stay inside d_ws, garbage discarded); y-store guarded.
__global__ __launch_bounds__(256) void k_scan(const float* __restrict__ dt,
                                              const unsigned short* __restrict__ xz,
                                              const unsigned short* __restrict__ ub,
                                              const unsigned short* __restrict__ xdb,
                                              const float* __restrict__ A_log,
                                              const float* __restrict__ Dv,
                                              unsigned short* __restrict__ yb) {
  int tid = threadIdx.x;
  int d = blockIdx.y * 256 + tid;
  int b = blockIdx.x;
  float Areg[D_STATE], hst[D_STATE];
#pragma unroll
  for (int n = 0; n < D_STATE; ++n) {
    Areg[n] = -__expf(A_log[d * D_STATE + n]);
    hst[n] = 0.f;
  }
  float Dd = Dv[d];
  size_t row0 = (size_t)b * SEQ;

  for (int t0 = 0; t0 < SEQ; t0 += ST) {
    int nt = SEQ - t0 < ST ? SEQ - t0 : ST;  // wave-uniform
    // ---- batch-issue u/z/dt loads ----
    float uv[ST], zv[ST], dtv[ST];
#pragma unroll
    for (int tt = 0; tt < ST; ++tt) {
      size_t m = row0 + t0 + tt;
      dtv[tt] = dt[m * D_INNER + d];
      uv[tt] = b2f(ub[m * D_INNER + d]);
      zv[tt] = b2f(xz[m * 2048 + 1024 + d]);
    }
#pragma unroll
    for (int tt = 0; tt < ST; ++tt)
      asm volatile("" :: "v"(uv[tt]), "v"(zv[tt]), "v"(dtv[tt]));
    // ---- sequential steps ----
#pragma unroll
    for (int tt = 0; tt < ST; ++tt) {
      size_t m = row0 + t0 + tt;
      const unsigned short* xp = xdb + m * 64 + 32;  // wave-uniform
      ushort8 b0 = *(const ushort8*)&xp[0];
      ushort8 b1 = *(const ushort8*)&xp[8];
      ushort8 c0 = *(const ushort8*)&xp[16];
      ushort8 c1 = *(const ushort8*)&xp[24];
      float du = dtv[tt] * uv[tt];
      float y0 = 0.f, y1 = 0.f, y2 = 0.f, y3 = 0.f;
#pragma unroll
      for (int j = 0; j < 8; ++j) {
        hst[j] = fmaf(__expf(dtv[tt] * Areg[j]), hst[j], du * b2f(b0[j]));
        float& yq = (j < 4) ? y0 : y1;
        yq = fmaf(hst[j], b2f(c0[j]), yq);
      }
#pragma unroll
      for (int j = 0; j < 8; ++j) {
        hst[8 + j] = fmaf(__expf(dtv[tt] * Areg[8 + j]), hst[8 + j], du * b2f(b1[j]));
        float& yq = (j < 4) ? y2 : y3;
        yq = fmaf(hst[8 + j], b2f(c1[j]), yq);
      }
      float y = (y0 + y1) + (y2 + y3);
      y = fmaf(Dd, uv[tt], y);
      y = y * (zv[tt] * sigmoidf_(zv[tt]));
      if (tt < nt) yb[m * D_INNER + d] = f2b(y);
    }
  }
}

extern "C" void kernel_launch(void* const* d_in, const int* in_sizes, int n_in,
                              void* d_out, int out_size, void* d_ws, size_t ws_size,
                              hipStream_t stream) {
  const float* x        = (const float*)d_in[0];
  const float* embed_W  = (const float*)d_in[2];
  const float* embed_b  = (const float*)d_in[3];
  const float* norm_w   = (const float*)d_in[4];
  const float* norm_b   = (const float*)d_in[5];
  const float* in_W     = (const float*)d_in[6];
  const float* conv_w   = (const float*)d_in[7];
  const float* conv_b   = (const float*)d_in[8];
  const float* xproj_W  = (const float*)d_in[9];
  const float* dtproj_W = (const float*)d_in[10];
  const float* dtproj_b = (const float*)d_in[11];
  const float* A_log    = (const float*)d_in[12];
  const float* Dskip    = (const float*)d_in[13];
  const float* out_W    = (const float*)d_in[14];
  const float* normf_w  = (const float*)d_in[15];
  const float* normf_b  = (const float*)d_in[16];
  const float* head_W   = (const float*)d_in[17];
  float* out = (float*)d_out;

  // fp32: res 512 + h 512 + dt 1024 = M*2048 (105.4 MB)
  // bf16: xz M*2048 + ub/yb M_PAD*2048 + xdb M_PAD*64 + weights (~1.8M)  (~110.8 MB)
  size_t f32_elems = (size_t)M_ROWS * 2048;
  size_t bf16_elems = (size_t)M_ROWS * 2048 + (size_t)M_PAD * 2048 + (size_t)M_PAD * 64 +
                      2048 * 512 + 512 * 1024 + 128 * 1024 + 1024 * 64;
  size_t need = f32_elems * 4 + bf16_elems * 2;
  if (ws_size < need) return;

  float* ws = (float*)d_ws;
  float* buf_res  = ws;                                   // M*512
  float* buf_h    = buf_res  + (size_t)M_ROWS * 512;      // M*512
  float* buf_dt   = buf_h    + (size_t)M_ROWS * 512;      // M*1024 fp32
  unsigned short* buf_xz   = (unsigned short*)(buf_dt + (size_t)M_ROWS * 1024); // M*2048
  unsigned short* buf_ub   = buf_xz + (size_t)M_ROWS * 2048;  // M_PAD*1024
  unsigned short* buf_yb   = buf_ub + (size_t)M_PAD * 1024;   // M_PAD*1024 (alias hnb)
  unsigned short* buf_hnb  = buf_yb;                          // M_PAD*512 (hn dead before scan)
  unsigned short* buf_xdb  = buf_yb + (size_t)M_PAD * 1024;   // M_PAD*64 (bf16 xdbl)
  unsigned short* buf_wib  = buf_xdb + (size_t)M_PAD * 64;    // 2048*512 (in_W; head_W later)
  unsigned short* buf_wob  = buf_wib + (size_t)2048 * 512;    // 512*1024 (out_W)
  unsigned short* buf_wxb  = buf_wob + (size_t)512 * 1024;    // 128*1024 (xproj_W padded)
  unsigned short* buf_wdtb = buf_wxb + (size_t)128 * 1024;    // 1024*64 (dtW col-padded)

  dim3 blk(256);

  k_embed<<<(M_ROWS * D_MODEL + 255) / 256, blk, 0, stream>>>(x, embed_W, embed_b, buf_h);

  for (int i = 0; i < NB_LAYERS; ++i) {
    // weights -> bf16 (per layer)
    k_f2b<<<(2048 * 512 + 255) / 256, blk, 0, stream>>>(
        in_W + (size_t)i * 2048 * D_MODEL, buf_wib, 2048 * 512, 2048 * 512);
    k_f2b<<<(512 * 1024 + 255) / 256, blk, 0, stream>>>(
        out_W + (size_t)i * D_MODEL * D_INNER, buf_wob, 512 * 1024, 512 * 1024);
    k_f2b<<<(128 * 1024 + 255) / 256, blk, 0, stream>>>(
        xproj_W + (size_t)i * 64 * D_INNER, buf_wxb, 64 * 1024, 128 * 1024);
    k_padW<<<(1024 * 64 + 255) / 256, blk, 0, stream>>>(
        dtproj_W + (size_t)i * D_INNER * DT_RANK, buf_wdtb, 1024, DT_RANK, 64);

    // residual update + layernorm -> hn (bf16)
    k_resid_norm<<<(M_ROWS + 3) / 4, blk, 0, stream>>>(
        buf_h, buf_res, nullptr, buf_hnb, norm_w + i * D_MODEL, norm_b + i * D_MODEL,
        i > 0 ? 1 : 0, 0);

    // in_proj (MFMA, bf16 out): xz = hn @ in_W^T   (M, 2048)
    k_gemm_mfma<1, 0><<<dim3(2048 / 128, M_PAD / 128), blk, 0, stream>>>(
        buf_hnb, buf_wib, nullptr, buf_xz, 2048, M_ROWS, 2048, 512);

    // conv + silu -> u (bf16)
    k_conv_silu<<<(M_ROWS * D_INNER + 255) / 256, blk, 0, stream>>>(
        buf_xz, conv_w + (size_t)i * D_INNER * D_CONV, conv_b + (size_t)i * D_INNER, buf_ub);

    // x_proj (MFMA, bf16 out): xdb = u @ xproj_W^T   (M, 64), N padded to 128
    k_gemm_mfma<1, 0><<<dim3(1, M_PAD / 128), blk, 0, stream>>>(
        buf_ub, buf_wxb, nullptr, buf_xdb, 64, M_ROWS, 64, 1024);

    // dt_proj (MFMA, fp32 out, softplus+bias): dt = softplus(xdb @ dtW^T + b)   (M, 1024)
    k_gemm_mfma<0, 1><<<dim3(1024 / 128, M_PAD / 128), blk, 0, stream>>>(
        buf_xdb, buf_wdtb, dtproj_b + (size_t)i * D_INNER, buf_dt, 1024, M_ROWS, 1024, 64);

    // selective scan -> y (bf16, overwrites hn region; hn is dead)
    k_scan<<<dim3(BATCH, D_INNER / 256), blk, 0, stream>>>(
        buf_dt, buf_xz, buf_ub, buf_xdb,
        A_log + (size_t)i * D_INNER * D_STATE, Dskip + (size_t)i * D_INNER, buf_yb);

    // out_proj (MFMA, fp32 out): h = y @ out_W^T   (M, 512)
    k_gemm_mfma<0, 0><<<dim3(512 / 128, M_PAD / 128), blk, 0, stream>>>(
        buf_yb, buf_wob, nullptr, buf_h, 512, M_ROWS, 512, 1024);
  }

  // final residual + rmsnorm -> xf (bf16, over hnb region; y dead)
  k_resid_norm<<<(M_ROWS + 3) / 4, blk, 0, stream>>>(
      buf_h, buf_res, nullptr, buf_hnb, normf_w, normf_b, 1, 1);

  // head_W -> bf16 padded to 256 rows (reuse in_W bf16 buffer — dead after last in_proj)
  k_f2b<<<(256 * 512 + 255) / 256, blk, 0, stream>>>(head_W, buf_wib, CITY * 512, 256 * 512);

  // head (MFMA, fp32 out): logits = xf @ head_W^T   (M, 200), N padded to 256
  k_gemm_mfma<0, 0><<<dim3(256 / 128, M_PAD / 128), blk, 0, stream>>>(
      buf_hnb, buf_wib, nullptr, out, CITY, M_ROWS, CITY, 512);
}

// Round 11
// 1034.061 us; speedup vs baseline: 1.0551x; 1.0551x over previous
//
#include <hip/hip_runtime.h>
#include <math.h>

#define D_MODEL 512
#define D_INNER 1024
#define DT_RANK 32
#define D_STATE 16
#define D_CONV 4
#define NB_LAYERS 3
#define BATCH 64
#define SEQ 201
#define CITY 200
#define M_ROWS (BATCH * SEQ)   // 12864 = 64*201
#define M_PAD 12928            // 128*101, for 128-row MFMA tiles
#define EPS 1e-5f
#define NCH 8                  // scan chunks
#define CL 26                  // chunk length (8*26=208 >= 201)

typedef __attribute__((ext_vector_type(8))) short short8;
typedef __attribute__((ext_vector_type(8))) unsigned short ushort8;
typedef __attribute__((ext_vector_type(4))) float f32x4;

__device__ __forceinline__ float sigmoidf_(float x) { return 1.f / (1.f + __expf(-x)); }

__device__ __forceinline__ unsigned short f2b(float f) {  // RNE fp32->bf16
  union { float f; unsigned int u; } v; v.f = f;
  unsigned int r = (v.u + 0x7fff + ((v.u >> 16) & 1)) >> 16;
  return (unsigned short)r;
}
__device__ __forceinline__ float b2f(unsigned short h) {
  union { unsigned int u; float f; } v; v.u = ((unsigned int)h) << 16; return v.f;
}

__device__ __forceinline__ void gload_lds16(const void* g, void* l) {
  __builtin_amdgcn_global_load_lds(
      (const __attribute__((address_space(1))) void*)g,
      (__attribute__((address_space(3))) void*)l, 16, 0, 0);
}

// ---------------- fp32 -> bf16 bulk convert (zero-pad tail to n_total) ----------------
__global__ __launch_bounds__(256) void k_f2b(const float* __restrict__ in,
                                             unsigned short* __restrict__ out,
                                             int n, int n_total) {
  int i = blockIdx.x * 256 + threadIdx.x;
  if (i < n) out[i] = f2b(in[i]);
  else if (i < n_total) out[i] = 0;
}

// ---------------- fp32 [rows][incols] -> bf16 [rows][outcols], zero col-pad ----------------
__global__ __launch_bounds__(256) void k_padW(const float* __restrict__ W,
                                              unsigned short* __restrict__ out,
                                              int rows, int incols, int outcols) {
  int i = blockIdx.x * 256 + threadIdx.x;
  if (i >= rows * outcols) return;
  int n = i / outcols, k = i - n * outcols;
  out[i] = (k < incols) ? f2b(W[(size_t)n * incols + k]) : 0;
}

// ---------------- embed ----------------
__global__ __launch_bounds__(256) void k_embed(const float* __restrict__ x,
                                               const float* __restrict__ W,
                                               const float* __restrict__ b,
                                               float* __restrict__ h) {
  int idx = blockIdx.x * 256 + threadIdx.x;
  if (idx >= M_ROWS * D_MODEL) return;
  int d = idx & (D_MODEL - 1);
  int m = idx >> 9;
  float x0 = x[m * 2 + 0], x1 = x[m * 2 + 1];
  h[idx] = fmaf(x0, W[d * 2 + 0], fmaf(x1, W[d * 2 + 1], b[d]));
}

// ---------------- fused residual add + LayerNorm / RMSNorm ----------------
__global__ __launch_bounds__(256) void k_resid_norm(const float* __restrict__ h,
                                                    float* __restrict__ resid,
                                                    float* __restrict__ out,
                                                    unsigned short* __restrict__ out_b,
                                                    const float* __restrict__ w,
                                                    const float* __restrict__ b,
                                                    int addRes, int mode) {
  int row = blockIdx.x * 4 + (threadIdx.x >> 6);
  int lane = threadIdx.x & 63;
  if (row >= M_ROWS) return;
  const float* hp = h + (size_t)row * D_MODEL;
  float* rp = resid + (size_t)row * D_MODEL;
  float v[8];
#pragma unroll
  for (int j = 0; j < 8; ++j) {
    float t = hp[j * 64 + lane];
    if (addRes) t += rp[j * 64 + lane];
    v[j] = t;
    rp[j * 64 + lane] = t;
  }
  float mu = 0.f, rstd;
  if (mode == 0) {
    float s = 0.f;
#pragma unroll
    for (int j = 0; j < 8; ++j) s += v[j];
#pragma unroll
    for (int o = 1; o < 64; o <<= 1) s += __shfl_xor(s, o);
    mu = s * (1.f / D_MODEL);
    float vs = 0.f;
#pragma unroll
    for (int j = 0; j < 8; ++j) { float d0 = v[j] - mu; vs += d0 * d0; }
#pragma unroll
    for (int o = 1; o < 64; o <<= 1) vs += __shfl_xor(vs, o);
    rstd = rsqrtf(vs * (1.f / D_MODEL) + EPS);
  } else {
    float s = 0.f;
#pragma unroll
    for (int j = 0; j < 8; ++j) s += v[j] * v[j];
#pragma unroll
    for (int o = 1; o < 64; o <<= 1) s += __shfl_xor(s, o);
    rstd = rsqrtf(s * (1.f / D_MODEL) + EPS);
  }
#pragma unroll
  for (int j = 0; j < 8; ++j) {
    int c = j * 64 + lane;
    float o = (v[j] - mu) * rstd * w[c] + b[c];
    if (out) out[(size_t)row * D_MODEL + c] = o;
    if (out_b) out_b[(size_t)row * D_MODEL + c] = f2b(o);
  }
}

// ---------------- bf16 MFMA GEMM: C[M,Nout] = A[M,K]bf16 @ B[N,K]bf16^T (+bias)(+softplus) --
template <int BOUT, int ACT>
__global__ __launch_bounds__(256) void k_gemm_mfma(const unsigned short* __restrict__ A,
                                                   const unsigned short* __restrict__ B,
                                                   const float* __restrict__ bias,
                                                   void* __restrict__ Cv, int ldc,
                                                   int M, int Nout, int K) {
  __shared__ unsigned short lA[128 * 64];
  __shared__ unsigned short lB[128 * 64];
  int tid = threadIdx.x;
  int wave = tid >> 6, lane = tid & 63;
  int bm = blockIdx.y * 128, bn = blockIdx.x * 128;
  int wm = (wave >> 1) * 64, wn = (wave & 1) * 64;
  f32x4 acc[4][4] = {};

  for (int k0 = 0; k0 < K; k0 += 64) {
#pragma unroll
    for (int i = 0; i < 4; ++i) {
      int e = (i * 256 + tid) * 8;   // flat bf16 element in [128][64] tile
      int r = e >> 6, c = e & 63;
      gload_lds16(A + (size_t)(bm + r) * K + k0 + c, &lA[e]);
      gload_lds16(B + (size_t)(bn + r) * K + k0 + c, &lB[e]);
    }
    __syncthreads();
#pragma unroll
    for (int ks = 0; ks < 2; ++ks) {
      int koff = ks * 32 + (lane >> 4) * 8;
      short8 a[4], b[4];
#pragma unroll
      for (int i = 0; i < 4; ++i)
        a[i] = *(const short8*)&lA[(wm + i * 16 + (lane & 15)) * 64 + koff];
#pragma unroll
      for (int j = 0; j < 4; ++j)
        b[j] = *(const short8*)&lB[(wn + j * 16 + (lane & 15)) * 64 + koff];
#pragma unroll
      for (int i = 0; i < 4; ++i)
#pragma unroll
        for (int j = 0; j < 4; ++j)
          acc[i][j] = __builtin_amdgcn_mfma_f32_16x16x32_bf16(a[i], b[j], acc[i][j], 0, 0, 0);
    }
    __syncthreads();
  }
  // C/D layout: col = lane&15, row = (lane>>4)*4 + reg   [m89-verified]
#pragma unroll
  for (int i = 0; i < 4; ++i) {
    int row0 = bm + wm + i * 16 + (lane >> 4) * 4;
#pragma unroll
    for (int j = 0; j < 4; ++j) {
      int col = bn + wn + j * 16 + (lane & 15);
#pragma unroll
      for (int r = 0; r < 4; ++r) {
        int m = row0 + r;
        if (m < M && col < Nout) {
          float v = acc[i][j][r];
          if (ACT) { v += bias[col]; v = (v > 20.f) ? v : __logf(1.f + __expf(v)); }
          if (BOUT) ((unsigned short*)Cv)[(size_t)m * ldc + col] = f2b(v);
          else ((float*)Cv)[(size_t)m * ldc + col] = v;
        }
      }
    }
  }
}

// ---------------- depthwise causal conv (width 4) + bias + SiLU; bf16 in/out --------------
__global__ __launch_bounds__(256) void k_conv_silu(const unsigned short* __restrict__ xz,
                                                   const float* __restrict__ cw,
                                                   const float* __restrict__ cb,
                                                   unsigned short* __restrict__ ub) {
  int idx = blockIdx.x * 256 + threadIdx.x;
  if (idx >= M_ROWS * D_INNER) return;
  int d = idx & (D_INNER - 1);
  int m = idx >> 10;
  int l = m % SEQ;
  float acc = cb[d];
#pragma unroll
  for (int k = 0; k < D_CONV; ++k) {
    int ls = l - (D_CONV - 1) + k;
    if (ls >= 0)
      acc = fmaf(cw[d * D_CONV + k], b2f(xz[(size_t)(m - (D_CONV - 1) + k) * 2048 + d]), acc);
  }
  ub[idx] = f2b(acc * sigmoidf_(acc));
}

// ---------------- chunked selective scan: pass 1 (local scans, h0=0) ----------------
// grid (BATCH*NCH, D_INNER/256). Stores local final state L (bf16[16]) + chunk dt-sum.
__global__ __launch_bounds__(256) void k_scan_p1(const float* __restrict__ dt,
                                                 const unsigned short* __restrict__ ub,
                                                 const unsigned short* __restrict__ xdb,
                                                 const float* __restrict__ A_log,
                                                 unsigned short* __restrict__ L,
                                                 float* __restrict__ dtsum) {
  int tid = threadIdx.x;
  int b = blockIdx.x >> 3, c = blockIdx.x & 7;
  int d = blockIdx.y * 256 + tid;
  int t0 = c * CL, t1 = t0 + CL < SEQ ? t0 + CL : SEQ;
  float Areg[D_STATE], hst[D_STATE];
#pragma unroll
  for (int n = 0; n < D_STATE; ++n) {
    Areg[n] = -__expf(A_log[d * D_STATE + n]);
    hst[n] = 0.f;
  }
  float ds = 0.f;
  size_t row0 = (size_t)b * SEQ;
  for (int t = t0; t < t1; ++t) {
    size_t m = row0 + t;
    float dtv = dt[m * D_INNER + d];
    float uv = b2f(ub[m * D_INNER + d]);
    const unsigned short* xp = xdb + m * 64 + 32;
    ushort8 b0 = *(const ushort8*)&xp[0];
    ushort8 b1 = *(const ushort8*)&xp[8];
    float du = dtv * uv;
    ds += dtv;
#pragma unroll
    for (int j = 0; j < 8; ++j)
      hst[j] = fmaf(__expf(dtv * Areg[j]), hst[j], du * b2f(b0[j]));
#pragma unroll
    for (int j = 0; j < 8; ++j)
      hst[8 + j] = fmaf(__expf(dtv * Areg[8 + j]), hst[8 + j], du * b2f(b1[j]));
  }
  size_t base = ((size_t)(b * NCH + c) * D_INNER + d) * D_STATE;
  ushort8 o0, o1;
#pragma unroll
  for (int j = 0; j < 8; ++j) { o0[j] = f2b(hst[j]); o1[j] = f2b(hst[8 + j]); }
  *(ushort8*)&L[base] = o0;
  *(ushort8*)&L[base + 8] = o1;
  dtsum[(size_t)(b * NCH + c) * D_INNER + d] = ds;
}

// ---------------- chunked scan: fixup (sequential chunk prefix; L -> entry states) --------
__global__ __launch_bounds__(256) void k_scan_fix(const float* __restrict__ A_log,
                                                  const float* __restrict__ dtsum,
                                                  unsigned short* __restrict__ L) {
  int tid = threadIdx.x;
  int b = blockIdx.x;
  int d = blockIdx.y * 256 + tid;
  float Areg[D_STATE], h[D_STATE];
#pragma unroll
  for (int n = 0; n < D_STATE; ++n) {
    Areg[n] = -__expf(A_log[d * D_STATE + n]);
    h[n] = 0.f;
  }
  for (int c = 0; c < NCH; ++c) {
    size_t base = ((size_t)(b * NCH + c) * D_INNER + d) * D_STATE;
    ushort8 l0 = *(const ushort8*)&L[base];
    ushort8 l1 = *(const ushort8*)&L[base + 8];
    float ds = dtsum[(size_t)(b * NCH + c) * D_INNER + d];
    // store entry state (state BEFORE chunk c) over L
    ushort8 o0, o1;
#pragma unroll
    for (int j = 0; j < 8; ++j) { o0[j] = f2b(h[j]); o1[j] = f2b(h[8 + j]); }
    *(ushort8*)&L[base] = o0;
    *(ushort8*)&L[base + 8] = o1;
    // advance: h = exp(A*ds)*h + local
#pragma unroll
    for (int j = 0; j < 8; ++j)
      h[j] = fmaf(__expf(Areg[j] * ds), h[j], b2f(l0[j]));
#pragma unroll
    for (int j = 0; j < 8; ++j)
      h[8 + j] = fmaf(__expf(Areg[8 + j] * ds), h[8 + j], b2f(l1[j]));
  }
}

// ---------------- chunked scan: pass 2 (full scan per chunk from entry state) -------------
__global__ __launch_bounds__(256) void k_scan_p2(const float* __restrict__ dt,
                                                 const unsigned short* __restrict__ xz,
                                                 const unsigned short* __restrict__ ub,
                                                 const unsigned short* __restrict__ xdb,
                                                 const float* __restrict__ A_log,
                                                 const float* __restrict__ Dv,
                                                 const unsigned short* __restrict__ L,
                                                 unsigned short* __restrict__ yb) {
  int tid = threadIdx.x;
  int b = blockIdx.x >> 3, c = blockIdx.x & 7;
  int d = blockIdx.y * 256 + tid;
  int t0 = c * CL, t1 = t0 + CL < SEQ ? t0 + CL : SEQ;
  float Areg[D_STATE], hst[D_STATE];
  size_t base = ((size_t)(b * NCH + c) * D_INNER + d) * D_STATE;
  ushort8 l0 = *(const ushort8*)&L[base];
  ushort8 l1 = *(const ushort8*)&L[base + 8];
#pragma unroll
  for (int n = 0; n < D_STATE; ++n) Areg[n] = -__expf(A_log[d * D_STATE + n]);
#pragma unroll
  for (int j = 0; j < 8; ++j) { hst[j] = b2f(l0[j]); hst[8 + j] = b2f(l1[j]); }
  float Dd = Dv[d];
  size_t row0 = (size_t)b * SEQ;
  for (int t = t0; t < t1; ++t) {
    size_t m = row0 + t;
    float dtv = dt[m * D_INNER + d];
    float uv = b2f(ub[m * D_INNER + d]);
    float zv = b2f(xz[m * 2048 + 1024 + d]);
    const unsigned short* xp = xdb + m * 64 + 32;
    ushort8 b0 = *(const ushort8*)&xp[0];
    ushort8 b1 = *(const ushort8*)&xp[8];
    ushort8 c0 = *(const ushort8*)&xp[16];
    ushort8 c1 = *(const ushort8*)&xp[24];
    float du = dtv * uv;
    float y0 = 0.f, y1 = 0.f, y2 = 0.f, y3 = 0.f;
#pragma unroll
    for (int j = 0; j < 8; ++j) {
      hst[j] = fmaf(__expf(dtv * Areg[j]), hst[j], du * b2f(b0[j]));
      float& yq = (j < 4) ? y0 : y1;
      yq = fmaf(hst[j], b2f(c0[j]), yq);
    }
#pragma unroll
    for (int j = 0; j < 8; ++j) {
      hst[8 + j] = fmaf(__expf(dtv * Areg[8 + j]), hst[8 + j], du * b2f(b1[j]));
      float& yq = (j < 4) ? y2 : y3;
      yq = fmaf(hst[8 + j], b2f(c1[j]), yq);
    }
    float y = (y0 + y1) + (y2 + y3);
    y = fmaf(Dd, uv, y);
    y = y * (zv * sigmoidf_(zv));
    yb[m * D_INNER + d] = f2b(y);
  }
}

extern "C" void kernel_launch(void* const* d_in, const int* in_sizes, int n_in,
                              void* d_out, int out_size, void* d_ws, size_t ws_size,
                              hipStream_t stream) {
  const float* x        = (const float*)d_in[0];
  const float* embed_W  = (const float*)d_in[2];
  const float* embed_b  = (const float*)d_in[3];
  const float* norm_w   = (const float*)d_in[4];
  const float* norm_b   = (const float*)d_in[5];
  const float* in_W     = (const float*)d_in[6];
  const float* conv_w   = (const float*)d_in[7];
  const float* conv_b   = (const float*)d_in[8];
  const float* xproj_W  = (const float*)d_in[9];
  const float* dtproj_W = (const float*)d_in[10];
  const float* dtproj_b = (const float*)d_in[11];
  const float* A_log    = (const float*)d_in[12];
  const float* Dskip    = (const float*)d_in[13];
  const float* out_W    = (const float*)d_in[14];
  const float* normf_w  = (const float*)d_in[15];
  const float* normf_b  = (const float*)d_in[16];
  const float* head_W   = (const float*)d_in[17];
  float* out = (float*)d_out;

  size_t f32_elems = (size_t)M_ROWS * 2048;
  size_t bf16_elems = (size_t)M_ROWS * 2048 + (size_t)M_PAD * 2048 + (size_t)M_PAD * 64 +
                      2048 * 512 + 512 * 1024 + 128 * 1024 + 1024 * 64;
  size_t need = f32_elems * 4 + bf16_elems * 2;
  if (ws_size < need) return;

  float* ws = (float*)d_ws;
  float* buf_res  = ws;                                   // M*512
  float* buf_h    = buf_res  + (size_t)M_ROWS * 512;      // M*512 (scan-phase scratch: L+dtsum)
  float* buf_dt   = buf_h    + (size_t)M_ROWS * 512;      // M*1024 fp32
  unsigned short* buf_xz   = (unsigned short*)(buf_dt + (size_t)M_ROWS * 1024); // M*2048
  unsigned short* buf_ub   = buf_xz + (size_t)M_ROWS * 2048;  // M_PAD*1024
  unsigned short* buf_yb   = buf_ub + (size_t)M_PAD * 1024;   // M_PAD*1024 (alias hnb)
  unsigned short* buf_hnb  = buf_yb;                          // M_PAD*512 (hn dead before scan)
  unsigned short* buf_xdb  = buf_yb + (size_t)M_PAD * 1024;   // M_PAD*64 (bf16 xdbl)
  unsigned short* buf_wib  = buf_xdb + (size_t)M_PAD * 64;    // 2048*512 (in_W; head_W later)
  unsigned short* buf_wob  = buf_wib + (size_t)2048 * 512;    // 512*1024 (out_W)
  unsigned short* buf_wxb  = buf_wob + (size_t)512 * 1024;    // 128*1024 (xproj_W padded)
  unsigned short* buf_wdtb = buf_wxb + (size_t)128 * 1024;    // 1024*64 (dtW col-padded)

  // scan scratch inside dead buf_h (26.3 MB): L = B*NCH*1024*16 bf16 (16.8 MB) + dtsum fp32 (2 MB)
  unsigned short* buf_L = (unsigned short*)buf_h;
  float* buf_dts = (float*)(buf_L + (size_t)BATCH * NCH * D_INNER * D_STATE);

  dim3 blk(256);

  k_embed<<<(M_ROWS * D_MODEL + 255) / 256, blk, 0, stream>>>(x, embed_W, embed_b, buf_h);

  for (int i = 0; i < NB_LAYERS; ++i) {
    // weights -> bf16 (per layer)
    k_f2b<<<(2048 * 512 + 255) / 256, blk, 0, stream>>>(
        in_W + (size_t)i * 2048 * D_MODEL, buf_wib, 2048 * 512, 2048 * 512);
    k_f2b<<<(512 * 1024 + 255) / 256, blk, 0, stream>>>(
        out_W + (size_t)i * D_MODEL * D_INNER, buf_wob, 512 * 1024, 512 * 1024);
    k_f2b<<<(128 * 1024 + 255) / 256, blk, 0, stream>>>(
        xproj_W + (size_t)i * 64 * D_INNER, buf_wxb, 64 * 1024, 128 * 1024);
    k_padW<<<(1024 * 64 + 255) / 256, blk, 0, stream>>>(
        dtproj_W + (size_t)i * D_INNER * DT_RANK, buf_wdtb, 1024, DT_RANK, 64);

    // residual update + layernorm -> hn (bf16)
    k_resid_norm<<<(M_ROWS + 3) / 4, blk, 0, stream>>>(
        buf_h, buf_res, nullptr, buf_hnb, norm_w + i * D_MODEL, norm_b + i * D_MODEL,
        i > 0 ? 1 : 0, 0);

    // in_proj (MFMA, bf16 out): xz = hn @ in_W^T   (M, 2048)
    k_gemm_mfma<1, 0><<<dim3(2048 / 128, M_PAD / 128), blk, 0, stream>>>(
        buf_hnb, buf_wib, nullptr, buf_xz, 2048, M_ROWS, 2048, 512);

    // conv + silu -> u (bf16)
    k_conv_silu<<<(M_ROWS * D_INNER + 255) / 256, blk, 0, stream>>>(
        buf_xz, conv_w + (size_t)i * D_INNER * D_CONV, conv_b + (size_t)i * D_INNER, buf_ub);

    // x_proj (MFMA, bf16 out): xdb = u @ xproj_W^T   (M, 64), N padded to 128
    k_gemm_mfma<1, 0><<<dim3(1, M_PAD / 128), blk, 0, stream>>>(
        buf_ub, buf_wxb, nullptr, buf_xdb, 64, M_ROWS, 64, 1024);

    // dt_proj (MFMA, fp32 out, softplus+bias): dt = softplus(xdb @ dtW^T + b)   (M, 1024)
    k_gemm_mfma<0, 1><<<dim3(1024 / 128, M_PAD / 128), blk, 0, stream>>>(
        buf_xdb, buf_wdtb, dtproj_b + (size_t)i * D_INNER, buf_dt, 1024, M_ROWS, 1024, 64);

    // chunked scan: pass1 (local) -> fixup (prefix) -> pass2 (emit y)
    const float* Ai = A_log + (size_t)i * D_INNER * D_STATE;
    k_scan_p1<<<dim3(BATCH * NCH, D_INNER / 256), blk, 0, stream>>>(
        buf_dt, buf_ub, buf_xdb, Ai, buf_L, buf_dts);
    k_scan_fix<<<dim3(BATCH, D_INNER / 256), blk, 0, stream>>>(Ai, buf_dts, buf_L);
    k_scan_p2<<<dim3(BATCH * NCH, D_INNER / 256), blk, 0, stream>>>(
        buf_dt, buf_xz, buf_ub, buf_xdb, Ai, Dskip + (size_t)i * D_INNER, buf_L, buf_yb);

    // out_proj (MFMA, fp32 out): h = y @ out_W^T   (M, 512)  — overwrites scan scratch
    k_gemm_mfma<0, 0><<<dim3(512 / 128, M_PAD / 128), blk, 0, stream>>>(
        buf_yb, buf_wob, nullptr, buf_h, 512, M_ROWS, 512, 1024);
  }

  // final residual + rmsnorm -> xf (bf16, over hnb region; y dead)
  k_resid_norm<<<(M_ROWS + 3) / 4, blk, 0, stream>>>(
      buf_h, buf_res, nullptr, buf_hnb, normf_w, normf_b, 1, 1);

  // head_W -> bf16 padded to 256 rows (reuse in_W bf16 buffer — dead after last in_proj)
  k_f2b<<<(256 * 512 + 255) / 256, blk, 0, stream>>>(head_W, buf_wib, CITY * 512, 256 * 512);

  // head (MFMA, fp32 out): logits = xf @ head_W^T   (M, 200), N padded to 256
  k_gemm_mfma<0, 0><<<dim3(256 / 128, M_PAD / 128), blk, 0, stream>>>(
      buf_hnb, buf_wib, nullptr, out, CITY, M_ROWS, CITY, 512);
}